// Round 2
// baseline (179.832 us; speedup 1.0000x reference)
//
#include <hip/hip_runtime.h>

// HashEmbedding: out[b,s,:] = embedding[hashed_ids[b,s], :]  (pure gather)
//
// DTYPES (settled by earlier forensics, unchanged):
//  * hashed_ids: int32  (d_in[1])
//  * embedding / output: float32 (d_in[2] / d_out). EMBED_DIM=1024 f32
//    = 4096 B/row = 256 x 16 B vectors.
//
// R5 = R4 with the compile fix: __builtin_nontemporal_store requires a NATIVE
// clang vector type, not HIP's uint4 class. Use ext_vector_type(4) u32x4.
//
// Shape (R4 theory, unchanged): each 256-thread block owns TOK_PER_BLOCK=8
// consecutive tokens.
//   1. Prefetch all 8 indices (wave-uniform -> scalar loads)
//   2. Issue all 8 independent 16 B gather loads (8 outstanding vmem/thread)
//   3. Drain into 8 nontemporal 16 B stores (streaming output must not evict
//      the 41 MB embedding table from L2/L3)

#define ROW_VEC       256     // 16 B chunks per f32 embedding row (1024*4/16)
#define NUM_BUCKETS   10000
#define TOK_PER_BLOCK 8

typedef unsigned int u32x4 __attribute__((ext_vector_type(4)));

__global__ __launch_bounds__(256) void HashEmbedding_46136538693901_kernel(
    const int* __restrict__ hashed_ids,   // [n_tokens] int32, values in [0, 10000)
    const u32x4* __restrict__ emb,        // [NUM_BUCKETS * ROW_VEC]
    u32x4* __restrict__ out,              // [n_tokens * ROW_VEC]
    int n_tokens)
{
    const int t0  = blockIdx.x * TOK_PER_BLOCK;   // first token of this block
    const int col = threadIdx.x;                  // 16 B chunk within the row

    // --- 1. prefetch indices (uniform across the block -> scalar path) ---
    int idx[TOK_PER_BLOCK];
#pragma unroll
    for (int t = 0; t < TOK_PER_BLOCK; ++t) {
        int r = t0 + t;
        idx[t] = (r < n_tokens) ? hashed_ids[r] : 0;
        if ((unsigned)idx[t] >= (unsigned)NUM_BUCKETS) idx[t] = 0;  // fault guard
    }

    // --- 2. issue all gathers back-to-back: 8 outstanding loads/thread ---
    u32x4 v[TOK_PER_BLOCK];
#pragma unroll
    for (int t = 0; t < TOK_PER_BLOCK; ++t) {
        v[t] = emb[(unsigned)(idx[t] * ROW_VEC + col)];
    }

    // --- 3. streaming stores, nontemporal (no reuse; keep L2 for the table) ---
#pragma unroll
    for (int t = 0; t < TOK_PER_BLOCK; ++t) {
        int r = t0 + t;
        if (r < n_tokens) {
            __builtin_nontemporal_store(v[t], &out[(size_t)r * ROW_VEC + col]);
        }
    }
}

extern "C" void kernel_launch(void* const* d_in, const int* in_sizes, int n_in,
                              void* d_out, int out_size, void* d_ws, size_t ws_size,
                              hipStream_t stream) {
    // setup_inputs dict order: input_ids [B*S] i32 (unused), hashed_ids [B*S] i32,
    // embedding [NUM_BUCKETS*1024] f32.
    const int*   hashed = (const int*)d_in[1];
    const u32x4* emb    = (const u32x4*)d_in[2];
    u32x4*       outp   = (u32x4*)d_out;

    int n_tokens = in_sizes[1];                                  // 32768
    int grid = (n_tokens + TOK_PER_BLOCK - 1) / TOK_PER_BLOCK;   // 4096 blocks
    HashEmbedding_46136538693901_kernel<<<grid, 256, 0, stream>>>(
        hashed, emb, outp, n_tokens);
}